// Round 17
// baseline (30227.200 us; speedup 1.0000x reference)
//
#include <hip/hip_runtime.h>
#include <hip/hip_bf16.h>

// EnvLSTM: T=4096, IN=MEM=OUT=1024, fp32 in/out.
// r8: np ref f64-class; state must be exact f64 (r14); consumer loads of c MUST
// be atomic/MALL-served (r15/r16: cached fan-out unfixable -- prefetch fills
// lines of future-step rows; remote atomics don't invalidate).
// r17 = r10 (last-known-good, 21ms recur) + two changes:
//   (1) per-step aggregate counters cnt[2][4096]: producers atomic_add after
//       publish-ACK; ONE poller thread per WG on ONE shared address
//       (poll traffic /128 vs r10's 128 pollers/WG).
//   (2) staging loads coalesced: thread tid loads slot[tid], slot[tid+512]
//       (8B lane-stride instructions; r12 lesson).
//   P1/P3: r8-verified VALU f64 GEMMs, unchanged.

typedef __attribute__((ext_vector_type(4))) float f32x4;

static constexpr int TSEQ = 4096;
typedef unsigned long long ull;

struct Ptr6 { const float* p[6]; };

__device__ inline void atomic_store_f64(double* p, double v) {
  __hip_atomic_store((ull*)p, __builtin_bit_cast(ull, v),
                     __ATOMIC_RELAXED, __HIP_MEMORY_SCOPE_AGENT);
}
__device__ inline double atomic_load_f64(const double* p) {
  ull u = __hip_atomic_load((const ull*)p, __ATOMIC_RELAXED, __HIP_MEMORY_SCOPE_AGENT);
  return __builtin_bit_cast(double, u);
}

// ---------------- init: cslots parity0, env boundary rows, counters ----------------
__global__ void init_k(const float* __restrict__ c0l, const float* __restrict__ c0r,
                       double* __restrict__ cslots, int* __restrict__ cnt,
                       float* __restrict__ env) {
  int tid = blockIdx.x * blockDim.x + threadIdx.x;  // grid 8*256 = 2048
  // counters: cnt[dir*4096 + t]; step 0 pre-completed (init provides c0)
  for (int i = tid; i < 8192; i += 2048)
    cnt[i] = (i == 0 || i == 4096) ? 128 : 0;
  if (tid < 1024) {
    double v = (double)c0l[tid];
    cslots[tid] = v;                        // dir0 parity0
    env[tid] = (float)v;                    // lenv[0]
  } else if (tid < 2048) {
    int j = tid - 1024;
    double v = (double)c0r[j];
    cslots[2048 + j] = v;                   // dir1 parity0
    env[(size_t)(TSEQ - 1) * 2048 + 1024 + j] = (float)v;  // renv[T-1]
  }
}

// ---------------- VALU f64 GEMM P1: Wx[4096][6144] = x @ W^T + b ----------------
// Stores f32 hi + bf16 lo. [r8-verified]
__global__ __launch_bounds__(256) void gemm_f64v_k(
    const float* __restrict__ A, Ptr6 B, Ptr6 BIAS,
    float* __restrict__ CH, __hip_bfloat16* __restrict__ CL) {
  __shared__ double As[16][66];
  __shared__ double Bs[16][66];
  const int tid = threadIdx.x;
  const int m0 = blockIdx.y * 64, n0 = blockIdx.x * 64;
  const int tx = tid & 15, ty = tid >> 4;
  const int lrow = tid >> 2, lkq = tid & 3;
  const float* bmat = B.p[n0 >> 10] + (size_t)(n0 & 1023) * 1024;

  double acc[4][4] = {};

  for (int k0 = 0; k0 < 1024; k0 += 16) {
    f32x4 va = *(const f32x4*)(A + (size_t)(m0 + lrow) * 1024 + k0 + lkq * 4);
    f32x4 vb = *(const f32x4*)(bmat + (size_t)lrow * 1024 + k0 + lkq * 4);
    __syncthreads();
#pragma unroll
    for (int e = 0; e < 4; ++e) {
      As[lkq * 4 + e][lrow] = (double)va[e];
      Bs[lkq * 4 + e][lrow] = (double)vb[e];
    }
    __syncthreads();
#pragma unroll
    for (int k = 0; k < 16; ++k) {
      double a[4], b[4];
#pragma unroll
      for (int i = 0; i < 4; ++i) a[i] = As[k][ty + 16 * i];
#pragma unroll
      for (int jj = 0; jj < 4; ++jj) b[jj] = Bs[k][tx + 16 * jj];
#pragma unroll
      for (int i = 0; i < 4; ++i)
#pragma unroll
        for (int jj = 0; jj < 4; ++jj)
          acc[i][jj] = fma(a[i], b[jj], acc[i][jj]);
    }
  }

#pragma unroll
  for (int i = 0; i < 4; ++i)
#pragma unroll
    for (int jj = 0; jj < 4; ++jj) {
      int row = m0 + ty + 16 * i;
      int col = n0 + tx + 16 * jj;
      double s = acc[i][jj] + (double)BIAS.p[col >> 10][col & 1023];
      size_t idx = (size_t)row * 6144 + col;
      float hi = (float)s;
      CH[idx] = hi;
      CL[idx] = __float2bfloat16((float)(s - (double)hi));
    }
}

// ---------------- persistent f64 recurrence: counter-aggregated sync ----------------
__global__ __launch_bounds__(512, 2) void recur_k(
    const float* __restrict__ u0, const float* __restrict__ u1, const float* __restrict__ u2,
    const float* __restrict__ u3, const float* __restrict__ u4, const float* __restrict__ u5,
    const float* __restrict__ WxH,           // [T][6144] f32 hi
    const __hip_bfloat16* __restrict__ WxL,  // [T][6144] bf16 lo
    double* __restrict__ cslots,             // [2 dir][2 parity][1024] f64
    int* __restrict__ cnt,                   // [2 dir][4096] per-step counters
    float* __restrict__ env)                 // [T][2048] f32
{
  const int bid = blockIdx.x;     // 0..255
  const int dir = bid >> 7;
  const int wg  = bid & 127;
  const int tid = threadIdx.x;    // 0..511
  const int wave = tid >> 6;      // 0..7
  const int lane = tid & 63;
  const int j = wg * 8 + wave;    // cell owned by this wave

  const float* Uf = dir ? u3 : u0;
  const float* Ui = dir ? u4 : u1;
  const float* Uc = dir ? u5 : u2;

  // U rows as f64 in VGPRs: lane covers k = q*64 + lane
  double wf[16], wi[16], wcc[16];
#pragma unroll
  for (int q = 0; q < 16; ++q) {
    const size_t idx = (size_t)j * 1024 + q * 64 + lane;
    wf[q] = (double)Uf[idx]; wi[q] = (double)Ui[idx]; wcc[q] = (double)Uc[idx];
  }

  __shared__ double cl[1024];
  double* slotbase = cslots + dir * 2048;
  int* cn_ = cnt + dir * 4096;
  const size_t wxoff = (size_t)dir * 3072 + j;
  float* envp = env + dir * 1024 + j;

  for (int t = 0; t < TSEQ - 1; ++t) {
    const int xr = dir ? (TSEQ - 1 - t) : t;
    const size_t base = (size_t)xr * 6144 + wxoff;
    // Wx prefetch (plain loads, stable data; overlaps the wait)
    const double wxf = (double)WxH[base] + (double)__bfloat162float(WxL[base]);
    const double wxi = (double)WxH[base + 1024] + (double)__bfloat162float(WxL[base + 1024]);
    const double wxg = (double)WxH[base + 2048] + (double)__bfloat162float(WxL[base + 2048]);

    // single-poller aggregate wait: all 128 producers of step t published
    if (tid == 0) {
      while (__hip_atomic_load(&cn_[t], __ATOMIC_RELAXED, __HIP_MEMORY_SCOPE_AGENT) < 128)
        __builtin_amdgcn_s_sleep(1);
    }
    __syncthreads();

    // stage c_t: coalesced atomic loads (8B lane-stride instructions)
    {
      const double* slot = slotbase + (size_t)(t & 1) * 1024;
      const double a = atomic_load_f64(slot + tid);
      const double b = atomic_load_f64(slot + tid + 512);
      cl[tid] = a;
      cl[tid + 512] = b;
    }
    __syncthreads();

    const double cold = cl[j];
    double sf = 0.0, si = 0.0, sg = 0.0;
#pragma unroll
    for (int q = 0; q < 16; ++q) {
      const double cc = cl[q * 64 + lane];
      sf = fma(wf[q], cc, sf);
      si = fma(wi[q], cc, si);
      sg = fma(wcc[q], cc, sg);
    }
#pragma unroll
    for (int off = 1; off < 64; off <<= 1) {
      sf += __shfl_xor(sf, off);
      si += __shfl_xor(si, off);
      sg += __shfl_xor(sg, off);
    }

    const double af = sf + wxf, ai = si + wxi, ag = sg + wxg;
    const double fgate = 1.0 / (1.0 + exp(-af));
    const double igate = 1.0 / (1.0 + exp(-ai));
    const double ggate = tanh(ag);
    const double cn = fgate * cold + igate * ggate;

    if (lane == 0) {
      atomic_store_f64(slotbase + (size_t)((t + 1) & 1) * 1024 + j, cn);
      const int er = dir ? (TSEQ - 2 - t) : (t + 1);
      envp[(size_t)er * 2048] = (float)cn;
    }
    __syncthreads();  // each wave drains vmcnt -> all 8 publishes ACKed at MALL
    if (tid == 0)
      __hip_atomic_fetch_add(&cn_[t + 1], 1, __ATOMIC_RELAXED, __HIP_MEMORY_SCOPE_AGENT);
  }
}

// ---------------- VALU f64 GEMM P3: out = tanh(env @ [wo|uo]^T + bo) ----------------
__global__ __launch_bounds__(256) void gemm_out_f64_k(
    const float* __restrict__ A, const float* __restrict__ wo,
    const float* __restrict__ uo, const float* __restrict__ bo,
    float* __restrict__ C) {
  __shared__ double As[16][66];
  __shared__ double Bs[16][66];
  const int tid = threadIdx.x;
  const int m0 = blockIdx.y * 64, n0 = blockIdx.x * 64;
  const int tx = tid & 15, ty = tid >> 4;
  const int lrow = tid >> 2, lkq = tid & 3;

  double acc[4][4] = {};

  for (int k0 = 0; k0 < 2048; k0 += 16) {
    f32x4 va = *(const f32x4*)(A + (size_t)(m0 + lrow) * 2048 + k0 + lkq * 4);
    const float* bsrc = (k0 < 1024)
        ? wo + (size_t)(n0 + lrow) * 1024 + k0 + lkq * 4
        : uo + (size_t)(n0 + lrow) * 1024 + (k0 - 1024) + lkq * 4;
    f32x4 vb = *(const f32x4*)bsrc;
    __syncthreads();
#pragma unroll
    for (int e = 0; e < 4; ++e) {
      As[lkq * 4 + e][lrow] = (double)va[e];
      Bs[lkq * 4 + e][lrow] = (double)vb[e];
    }
    __syncthreads();
#pragma unroll
    for (int k = 0; k < 16; ++k) {
      double a[4], b[4];
#pragma unroll
      for (int i = 0; i < 4; ++i) a[i] = As[k][ty + 16 * i];
#pragma unroll
      for (int jj = 0; jj < 4; ++jj) b[jj] = Bs[k][tx + 16 * jj];
#pragma unroll
      for (int i = 0; i < 4; ++i)
#pragma unroll
        for (int jj = 0; jj < 4; ++jj)
          acc[i][jj] = fma(a[i], b[jj], acc[i][jj]);
    }
  }

#pragma unroll
  for (int i = 0; i < 4; ++i)
#pragma unroll
    for (int jj = 0; jj < 4; ++jj) {
      int row = m0 + ty + 16 * i;
      int col = n0 + tx + 16 * jj;
      double s = acc[i][jj] + (double)bo[col];
      C[(size_t)row * 1024 + col] = (float)tanh(s);
    }
}

// ---------------- launch ----------------
extern "C" void kernel_launch(void* const* d_in, const int* in_sizes, int n_in,
                              void* d_out, int out_size, void* d_ws, size_t ws_size,
                              hipStream_t stream) {
  if (n_in < 24) return;
  const float* x    = (const float*)d_in[0];
  const float* wf_l = (const float*)d_in[1];
  const float* uf_l = (const float*)d_in[2];
  const float* bf_l = (const float*)d_in[3];
  const float* wi_l = (const float*)d_in[4];
  const float* ui_l = (const float*)d_in[5];
  const float* bi_l = (const float*)d_in[6];
  const float* wc_l = (const float*)d_in[7];
  const float* uc_l = (const float*)d_in[8];
  const float* bc_l = (const float*)d_in[9];
  const float* wf_r = (const float*)d_in[10];
  const float* uf_r = (const float*)d_in[11];
  const float* bf_r = (const float*)d_in[12];
  const float* wi_r = (const float*)d_in[13];
  const float* ui_r = (const float*)d_in[14];
  const float* bi_r = (const float*)d_in[15];
  const float* wc_r = (const float*)d_in[16];
  const float* uc_r = (const float*)d_in[17];
  const float* bc_r = (const float*)d_in[18];
  const float* wo   = (const float*)d_in[19];
  const float* uo   = (const float*)d_in[20];
  const float* bo   = (const float*)d_in[21];
  const float* c0l  = (const float*)d_in[22];
  const float* c0r  = (const float*)d_in[23];

  const size_t NWX = (size_t)TSEQ * 6144;
  char* p = (char*)d_ws;
  auto carve = [&](size_t bytes) -> char* {
    char* r = p; p += (bytes + 255) & ~(size_t)255; return r;
  };
  float*          WxH  = (float*)carve(NWX * 4);                  // 100.7 MB
  __hip_bfloat16* WxL  = (__hip_bfloat16*)carve(NWX * 2);         //  50.3 MB
  float*          envc = (float*)carve((size_t)TSEQ * 2048 * 4);  //  33.6 MB
  double*         cslots = (double*)carve(4096 * 8);              //  32 KB
  int*            cnt    = (int*)carve(8192 * 4);                 //  32 KB
  if ((size_t)(p - (char*)d_ws) > ws_size) return;  // ~184.7 MB <= proven 210

  init_k<<<8, 256, 0, stream>>>(c0l, c0r, cslots, cnt, envc);

  Ptr6 Bw{{wf_l, wi_l, wc_l, wf_r, wi_r, wc_r}};
  Ptr6 Bb{{bf_l, bi_l, bc_l, bf_r, bi_r, bc_r}};
  gemm_f64v_k<<<dim3(96, 64), 256, 0, stream>>>(x, Bw, Bb, WxH, WxL);

  recur_k<<<256, 512, 0, stream>>>(uf_l, ui_l, uc_l, uf_r, ui_r, uc_r,
                                   WxH, WxL, cslots, cnt, envc);

  gemm_out_f64_k<<<dim3(16, 64), 256, 0, stream>>>(envc, wo, uo, bo, (float*)d_out);
}